// Round 5
// baseline (592.924 us; speedup 1.0000x reference)
//
#include <hip/hip_runtime.h>
#include <hip/hip_bf16.h>

#define TT 2048
#define CCH 1024
#define HH 16
#define DD 64
#define BB 4
#define MM (BB*TT)

typedef __attribute__((ext_vector_type(4))) float f32x4;
typedef __attribute__((ext_vector_type(8))) short short8;
typedef __attribute__((ext_vector_type(8))) unsigned short u16x8;
typedef __attribute__((ext_vector_type(4))) unsigned short u16x4;

__device__ __forceinline__ unsigned short f2b(float f) {
    // fp32 -> bf16 round-to-nearest-even (finite inputs)
    unsigned int u = __float_as_uint(f);
    u += 0x7fffu + ((u >> 16) & 1u);
    return (unsigned short)(u >> 16);
}
__device__ __forceinline__ float b2f(unsigned short u) {
    return __uint_as_float(((unsigned int)u) << 16);
}
__device__ __forceinline__ int finite_f(float v) {
    return ((__float_as_uint(v) >> 23) & 0xFFu) != 0xFFu;
}

// ---------------- input-dtype detector ----------------
// If low u16 of each u32 word looks like a bf16 of ~N(0,1) data (exponent in
// [0x62,0x90] or exact zero), the buffer is bf16 (~100% pass). True fp32: low
// u16 = random mantissa bits (~18% pass).
__global__ __launch_bounds__(64) void detect_k(const unsigned int* __restrict__ x,
                                               int* __restrict__ flag) {
    int tid = threadIdx.x;
    int cnt = 0;
#pragma unroll
    for (int i = 0; i < 16; ++i) {
        unsigned int w = x[tid * 16 + i];
        unsigned int lo = w & 0xFFFFu;
        unsigned int e = (lo >> 7) & 0xFFu;
        if ((e >= 0x62u && e <= 0x90u) || lo == 0u) ++cnt;
    }
#pragma unroll
    for (int o = 32; o; o >>= 1) cnt += __shfl_down(cnt, o);
    if (tid == 0) *flag = (cnt >= 640) ? 1 : 0;   // of 1024
}

// ------------- W transpose(+cast): [R][Cc] -> bf16 [Cc][R] -------------
__global__ __launch_bounds__(256) void wtrans_k(const void* __restrict__ in,
                                                unsigned short* __restrict__ out,
                                                int R, int Cc,
                                                const int* __restrict__ flag) {
    __shared__ float tile[32][33];
    const int tid = threadIdx.x;
    const int c0 = blockIdx.x * 32, r0 = blockIdx.y * 32;
    const int isb = *flag;
#pragma unroll
    for (int i = 0; i < 4; ++i) {
        int e = i * 256 + tid;
        int row = e >> 5, col = e & 31;
        size_t idx = (size_t)(r0 + row) * Cc + (c0 + col);
        tile[row][col] = isb ? b2f(((const unsigned short*)in)[idx])
                             : ((const float*)in)[idx];
    }
    __syncthreads();
#pragma unroll
    for (int i = 0; i < 4; ++i) {
        int e = i * 256 + tid;
        int crow = e >> 5, rcol = e & 31;
        out[(size_t)(c0 + crow) * R + (r0 + rcol)] = f2b(tile[rcol][crow]);
    }
}

// ------------- V transpose: bf16 [bh][2048][64] -> [bh][64][2048] -------------
__global__ __launch_bounds__(256) void vtrans_k(const unsigned short* __restrict__ V,
                                                unsigned short* __restrict__ VT) {
    __shared__ unsigned short tile[64][68];
    const int tid = threadIdx.x;
    const int t0 = blockIdx.x * 64;
    const int bh = blockIdx.y;
    const unsigned short* in = V + ((size_t)bh * TT + t0) * DD;
#pragma unroll
    for (int i = 0; i < 4; ++i) {
        int cid = i * 256 + tid;
        int row = cid >> 4;
        int ch  = cid & 15;
        u16x4 v = *(const u16x4*)(in + row * DD + ch * 4);
        *(u16x4*)&tile[row][ch * 4] = v;
    }
    __syncthreads();
    unsigned short* out = VT + (size_t)bh * DD * TT + t0;
#pragma unroll
    for (int i = 0; i < 4; ++i) {
        int cid = i * 256 + tid;
        int drow = cid >> 4;
        int tch  = cid & 15;
        u16x4 v;
        v[0] = tile[tch * 4 + 0][drow];
        v[1] = tile[tch * 4 + 1][drow];
        v[2] = tile[tch * 4 + 2][drow];
        v[3] = tile[tch * 4 + 3][drow];
        *(u16x4*)(out + (size_t)drow * TT + tch * 4) = v;
    }
}

// -------- QKV GEMM: x[M][K] (fp32|bf16) @ WqkvT[N][K] bf16 + bias --------
// scatter: Q (x0.125) -> Qb, K -> Kb  ([B,H,T,D] bf16);  V -> d_out (scratch)
__global__ __launch_bounds__(256) void gemm_qkv(const void* __restrict__ x,
                                                const unsigned short* __restrict__ Bt,
                                                const void* __restrict__ bias,
                                                unsigned short* __restrict__ outQ,
                                                unsigned short* __restrict__ outK,
                                                unsigned short* __restrict__ outV,
                                                const int* __restrict__ flag) {
    __shared__ unsigned short As[128 * 32];
    __shared__ unsigned short Bs[128 * 32];
    const int Ksz = CCH;
    const int tid = threadIdx.x;
    const int lane = tid & 63;
    const int wid = tid >> 6;
    const int bm = blockIdx.y * 128;
    const int bn = blockIdx.x * 128;
    const int wm = (wid >> 1) * 64;
    const int wn = (wid & 1) * 64;
    const int sr = tid >> 2;
    const int sc = (tid & 3) * 8;
    const int l15 = lane & 15, l4 = lane >> 4;
    const int isb = *flag;

    f32x4 acc[4][4];
#pragma unroll
    for (int i = 0; i < 4; ++i)
#pragma unroll
        for (int j = 0; j < 4; ++j)
            acc[i][j] = (f32x4){0.f, 0.f, 0.f, 0.f};

    const size_t aoff0 = (size_t)(bm + sr) * Ksz + sc;
    const size_t aoff1 = aoff0 + (size_t)64 * Ksz;
    const unsigned short* pb0 = Bt + (size_t)(bn + sr) * Ksz + sc;
    const unsigned short* pb1 = pb0 + (size_t)64 * Ksz;

    // load 8 A elements at element-offset `off`, convert to bf16 if needed
    auto lda = [&](size_t off) -> u16x8 {
        if (isb) return *(const u16x8*)((const unsigned short*)x + off);
        const float4* p = (const float4*)((const float*)x + off);
        float4 v0 = p[0], v1 = p[1];
        u16x8 o;
        o[0] = f2b(v0.x); o[1] = f2b(v0.y); o[2] = f2b(v0.z); o[3] = f2b(v0.w);
        o[4] = f2b(v1.x); o[5] = f2b(v1.y); o[6] = f2b(v1.z); o[7] = f2b(v1.w);
        return o;
    };

    u16x8 a0 = lda(aoff0);
    u16x8 a1 = lda(aoff1);
    u16x8 b0 = *(const u16x8*)(pb0);
    u16x8 b1 = *(const u16x8*)(pb1);

    for (int kt = 0; kt < Ksz; kt += 32) {
        __syncthreads();   // WAR: previous iter's frag reads complete
        *(u16x8*)&As[sr * 32 + sc] = a0;
        *(u16x8*)&As[(sr + 64) * 32 + sc] = a1;
        *(u16x8*)&Bs[sr * 32 + sc] = b0;
        *(u16x8*)&Bs[(sr + 64) * 32 + sc] = b1;
        if (kt + 32 < Ksz) {  // prefetch next K-slab
            a0 = lda(aoff0 + kt + 32);
            a1 = lda(aoff1 + kt + 32);
            b0 = *(const u16x8*)(pb0 + kt + 32);
            b1 = *(const u16x8*)(pb1 + kt + 32);
        }
        __syncthreads();
        short8 af[4], bfr[4];
#pragma unroll
        for (int mi = 0; mi < 4; ++mi)
            af[mi] = *(const short8*)&As[(wm + mi * 16 + l15) * 32 + l4 * 8];
#pragma unroll
        for (int ni = 0; ni < 4; ++ni)
            bfr[ni] = *(const short8*)&Bs[(wn + ni * 16 + l15) * 32 + l4 * 8];
#pragma unroll
        for (int mi = 0; mi < 4; ++mi)
#pragma unroll
            for (int ni = 0; ni < 4; ++ni)
                acc[mi][ni] = __builtin_amdgcn_mfma_f32_16x16x32_bf16(
                    af[mi], bfr[ni], acc[mi][ni], 0, 0, 0);
    }

    // epilogue: C/D layout col=lane&15, row=(lane>>4)*4+reg  [m89/m91]
#pragma unroll
    for (int mi = 0; mi < 4; ++mi) {
#pragma unroll
        for (int ni = 0; ni < 4; ++ni) {
            const int col = bn + wn + ni * 16 + l15;
            const float bv = isb ? b2f(((const unsigned short*)bias)[col])
                                 : ((const float*)bias)[col];
#pragma unroll
            for (int r = 0; r < 4; ++r) {
                const int row = bm + wm + mi * 16 + l4 * 4 + r;
                float v = acc[mi][ni][r] + bv;
                const int which = col >> 10;
                const int h = (col >> 6) & 15;
                const int d = col & 63;
                const int b = row >> 11, t = row & 2047;
                const size_t idx = (((size_t)b * HH + h) * TT + t) * DD + d;
                if (which == 0)      outQ[idx] = f2b(v * 0.125f);  // fold 1/sqrt(D)
                else if (which == 1) outK[idx] = f2b(v);
                else                 outV[idx] = f2b(v);
            }
        }
    }
}

// ---------------- flash attention: 1 wave per 16 q-rows ----------------
// Q,K: [bh][T][D] bf16 (Q pre-scaled by 0.125); VT: [bh][D][T] bf16
// Output written IN-PLACE over Q rows ([b][h][t][d] layout): each wave reads
// only its own 16 Q rows (hoisted to regs) and writes only those rows.
__global__ __launch_bounds__(256) void attn_k(unsigned short* __restrict__ Q,
                                              const unsigned short* __restrict__ K,
                                              const unsigned short* __restrict__ VT) {
    __shared__ unsigned short Plds[4][16][32];
    __shared__ unsigned short Olds[4][64][16];
    const int tid = threadIdx.x, lane = tid & 63, wid = tid >> 6;
    const int gw = blockIdx.x * 4 + wid;        // 0..8191
    const int bh = gw >> 7;                     // 0..63
    const int qw = (gw & 127) << 4;             // q-tile base
    const int l15 = lane & 15, l4 = lane >> 4;
    unsigned short* Qp = Q + (size_t)bh * TT * DD;
    const unsigned short* Kp = K + (size_t)bh * TT * DD;
    const unsigned short* Vp = VT + (size_t)bh * DD * TT;

    short8 qf[2];
    qf[0] = *(const short8*)(Qp + (qw + l15) * DD + l4 * 8);
    qf[1] = *(const short8*)(Qp + (qw + l15) * DD + 32 + l4 * 8);

    f32x4 ot[4];
#pragma unroll
    for (int c = 0; c < 4; ++c) ot[c] = (f32x4){0.f, 0.f, 0.f, 0.f};
    float m = -1e30f, lsum = 0.f;
    const int qi = qw + l15;
    const int kend = qw + 16;

    for (int kb = 0; kb < kend; kb += 32) {
        // S^T[kpos][q] = K . Q^T  (swapped operands: row-local softmax)
        f32x4 st[2];
#pragma unroll
        for (int t16 = 0; t16 < 2; ++t16) {
            short8 kf0 = *(const short8*)(Kp + (kb + t16 * 16 + l15) * DD + l4 * 8);
            short8 kf1 = *(const short8*)(Kp + (kb + t16 * 16 + l15) * DD + 32 + l4 * 8);
            f32x4 z = (f32x4){0.f, 0.f, 0.f, 0.f};
            z = __builtin_amdgcn_mfma_f32_16x16x32_bf16(kf0, qf[0], z, 0, 0, 0);
            z = __builtin_amdgcn_mfma_f32_16x16x32_bf16(kf1, qf[1], z, 0, 0, 0);
            st[t16] = z;
        }
        // causal mask + row max (row = q = l15; kpos across l4*4+r and t16)
        float sv[8];
        float tmax = -1e30f;
#pragma unroll
        for (int t16 = 0; t16 < 2; ++t16)
#pragma unroll
            for (int r = 0; r < 4; ++r) {
                const int kpos = kb + t16 * 16 + l4 * 4 + r;
                float v = st[t16][r];
                v = (kpos > qi) ? -30000.f : v;
                sv[t16 * 4 + r] = v;
                tmax = fmaxf(tmax, v);
            }
        tmax = fmaxf(tmax, __shfl_xor(tmax, 16));
        tmax = fmaxf(tmax, __shfl_xor(tmax, 32));
        const float mnew = fmaxf(m, tmax);
        const float corr = __expf(m - mnew);
        float psum = 0.f;
        unsigned short pb16[8];
#pragma unroll
        for (int i = 0; i < 8; ++i) {
            float p = __expf(sv[i] - mnew);
            psum += p;
            pb16[i] = f2b(p);
        }
        lsum = lsum * corr + psum;   // per-lane partial (8 of 32 kpos); reduced in epilogue
        m = mnew;
#pragma unroll
        for (int c = 0; c < 4; ++c) ot[c] *= corr;
        // P -> LDS [q][kpos], read back as PV B-fragment
        u16x4 w0, w1;
        w0[0] = pb16[0]; w0[1] = pb16[1]; w0[2] = pb16[2]; w0[3] = pb16[3];
        w1[0] = pb16[4]; w1[1] = pb16[5]; w1[2] = pb16[6]; w1[3] = pb16[7];
        *(u16x4*)&Plds[wid][l15][l4 * 4] = w0;
        *(u16x4*)&Plds[wid][l15][16 + l4 * 4] = w1;
        asm volatile("" ::: "memory");   // order LDS write -> read
        short8 pb = *(const short8*)&Plds[wid][l15][l4 * 8];
        // O^T[d][q] += V^T[d][kpos] . P[kpos][q]
#pragma unroll
        for (int c = 0; c < 4; ++c) {
            short8 vf = *(const short8*)(Vp + (size_t)(c * 16 + l15) * TT + kb + l4 * 8);
            ot[c] = __builtin_amdgcn_mfma_f32_16x16x32_bf16(vf, pb, ot[c], 0, 0, 0);
        }
    }

    // ---- THE FIX: row denominator = sum of the 4 l4-group partials ----
    // (m/corr were always row-uniform, so partials share one scale; lanes
    // l15==q, l4=0..3 differ only in bits 4,5 -> xor 16 + xor 32 sums them)
    float ls = lsum + __shfl_xor(lsum, 16);
    ls += __shfl_xor(ls, 32);

    // epilogue: normalize (canary 200 for non-finite), transpose via LDS,
    // write back over this wave's own Q rows
    const float inv = 1.f / ls;
#pragma unroll
    for (int c = 0; c < 4; ++c)
#pragma unroll
        for (int r = 0; r < 4; ++r) {
            float v = ot[c][r] * inv;
            if (!finite_f(v)) v = 200.0f;   // canary: attention-stage corruption
            Olds[wid][c * 16 + l4 * 4 + r][l15] = f2b(v);
        }
    asm volatile("" ::: "memory");       // order LDS write -> read
    const int q2 = lane >> 2, c8 = lane & 3;
#pragma unroll
    for (int s = 0; s < 2; ++s) {
        u16x8 o;
#pragma unroll
        for (int j = 0; j < 8; ++j) o[j] = Olds[wid][s * 32 + c8 * 8 + j][q2];
        *(u16x8*)(Qp + (size_t)(qw + q2) * DD + s * 32 + c8 * 8) = o;
    }
}

// -------- proj GEMM: Y([b][h][t][d] in Q region) @ WprojT + bias -> out fp32 --------
__global__ __launch_bounds__(256) void gemm_proj(const unsigned short* __restrict__ A,
                                                 const unsigned short* __restrict__ Bt,
                                                 const void* __restrict__ bias,
                                                 float* __restrict__ outO,
                                                 const int* __restrict__ flag) {
    __shared__ unsigned short As[128 * 32];
    __shared__ unsigned short Bs[128 * 32];
    const int Ksz = CCH;
    const int tid = threadIdx.x;
    const int lane = tid & 63;
    const int wid = tid >> 6;
    const int bm = blockIdx.y * 128;
    const int bn = blockIdx.x * 128;
    const int wm = (wid >> 1) * 64;
    const int wn = (wid & 1) * 64;
    const int sr = tid >> 2;
    const int sc = (tid & 3) * 8;
    const int l15 = lane & 15, l4 = lane >> 4;
    const int isb = *flag;

    f32x4 acc[4][4];
#pragma unroll
    for (int i = 0; i < 4; ++i)
#pragma unroll
        for (int j = 0; j < 4; ++j)
            acc[i][j] = (f32x4){0.f, 0.f, 0.f, 0.f};

    // A logical row m = b*2048+t, col k = h*64+d; stored [b][h][t][d]:
    // addr = b*(16*2048*64) + (k>>6)*(2048*64) + t*64 + (k&63)
    const int m0 = bm + sr;
    const unsigned short* Ar0 = A + (size_t)(m0 >> 11) * (HH * TT * DD)
                                  + (size_t)(m0 & 2047) * DD;
    const unsigned short* Ar1 = Ar0 + (size_t)64 * DD;   // row m0+64: same b, t+64
    const unsigned short* pb0 = Bt + (size_t)(bn + sr) * Ksz + sc;
    const unsigned short* pb1 = pb0 + (size_t)64 * Ksz;

    auto aoff = [&](int kt) -> size_t {   // kt%64 in {0,32}; slab stays in one h
        return (size_t)(kt >> 6) * (TT * DD) + (kt & 32) + sc;
    };

    u16x8 a0 = *(const u16x8*)(Ar0 + aoff(0));
    u16x8 a1 = *(const u16x8*)(Ar1 + aoff(0));
    u16x8 b0 = *(const u16x8*)(pb0);
    u16x8 b1 = *(const u16x8*)(pb1);

    for (int kt = 0; kt < Ksz; kt += 32) {
        __syncthreads();
        *(u16x8*)&As[sr * 32 + sc] = a0;
        *(u16x8*)&As[(sr + 64) * 32 + sc] = a1;
        *(u16x8*)&Bs[sr * 32 + sc] = b0;
        *(u16x8*)&Bs[(sr + 64) * 32 + sc] = b1;
        if (kt + 32 < Ksz) {
            a0 = *(const u16x8*)(Ar0 + aoff(kt + 32));
            a1 = *(const u16x8*)(Ar1 + aoff(kt + 32));
            b0 = *(const u16x8*)(pb0 + kt + 32);
            b1 = *(const u16x8*)(pb1 + kt + 32);
        }
        __syncthreads();
        short8 af[4], bfr[4];
#pragma unroll
        for (int mi = 0; mi < 4; ++mi)
            af[mi] = *(const short8*)&As[(wm + mi * 16 + l15) * 32 + l4 * 8];
#pragma unroll
        for (int ni = 0; ni < 4; ++ni)
            bfr[ni] = *(const short8*)&Bs[(wn + ni * 16 + l15) * 32 + l4 * 8];
#pragma unroll
        for (int mi = 0; mi < 4; ++mi)
#pragma unroll
            for (int ni = 0; ni < 4; ++ni)
                acc[mi][ni] = __builtin_amdgcn_mfma_f32_16x16x32_bf16(
                    af[mi], bfr[ni], acc[mi][ni], 0, 0, 0);
    }

#pragma unroll
    for (int mi = 0; mi < 4; ++mi) {
#pragma unroll
        for (int ni = 0; ni < 4; ++ni) {
            const int col = bn + wn + ni * 16 + l15;
            const float bv = isb ? b2f(((const unsigned short*)bias)[col])
                                 : ((const float*)bias)[col];
#pragma unroll
            for (int r = 0; r < 4; ++r) {
                const int row = bm + wm + mi * 16 + l4 * 4 + r;
                float v = acc[mi][ni][r] + bv;
                if (!finite_f(v)) v = 300.0f;   // canary: proj-stage corruption
                outO[(size_t)row * CCH + col] = v;   // fp32 output (reference dtype)
            }
        }
    }
}

extern "C" void kernel_launch(void* const* d_in, const int* in_sizes, int n_in,
                              void* d_out, int out_size, void* d_ws, size_t ws_size,
                              hipStream_t stream) {
    const void* x     = d_in[0];
    const void* Wqkv  = d_in[1];
    const void* bqkv  = d_in[2];
    const void* Wproj = d_in[3];
    const void* bproj = d_in[4];
    float* out = (float*)d_out;   // fp32 output (reference's output dtype)

    // workspace layout: 58.7 MB total (fits 64 MiB)
    char* w = (char*)d_ws;
    int* flag = (int*)w;                          w += 256;
    unsigned short* wqkvT  = (unsigned short*)w;  w += (size_t)3 * CCH * CCH * 2; // 6.3 MB
    unsigned short* wprojT = (unsigned short*)w;  w += (size_t)CCH * CCH * 2;     // 2.1 MB
    unsigned short* Qb     = (unsigned short*)w;  w += (size_t)MM * CCH * 2;      // 16.8 MB
    unsigned short* Kb     = (unsigned short*)w;  w += (size_t)MM * CCH * 2;      // 16.8 MB
    unsigned short* VTb    = (unsigned short*)w;  w += (size_t)MM * CCH * 2;      // 16.8 MB
    unsigned short* Vstage = (unsigned short*)d_out;  // d_out as V scratch (dead before final write)

    detect_k<<<1, 64, 0, stream>>>((const unsigned int*)x, flag);
    wtrans_k<<<dim3(96, 32), 256, 0, stream>>>(Wqkv, wqkvT, CCH, 3 * CCH, flag);
    wtrans_k<<<dim3(32, 32), 256, 0, stream>>>(Wproj, wprojT, CCH, CCH, flag);
    gemm_qkv<<<dim3(24, 64), 256, 0, stream>>>(x, wqkvT, bqkv, Qb, Kb, Vstage, flag);
    vtrans_k<<<dim3(32, 64), 256, 0, stream>>>(Vstage, VTb);
    attn_k<<<2048, 256, 0, stream>>>(Qb, Kb, VTb);          // writes Y over Q rows
    gemm_proj<<<dim3(8, 64), 256, 0, stream>>>(Qb, wprojT, bproj, out, flag);
}

// Round 7
// 439.719 us; speedup vs baseline: 1.3484x; 1.3484x over previous
//
#include <hip/hip_runtime.h>
#include <hip/hip_bf16.h>

#define TT 2048
#define CCH 1024
#define HH 16
#define DD 64
#define BB 4
#define MM (BB*TT)

typedef __attribute__((ext_vector_type(4))) float f32x4;
typedef __attribute__((ext_vector_type(8))) short short8;
typedef __attribute__((ext_vector_type(8))) unsigned short u16x8;
typedef __attribute__((ext_vector_type(4))) unsigned short u16x4;

__device__ __forceinline__ unsigned short f2b(float f) {
    // fp32 -> bf16 round-to-nearest-even (finite inputs)
    unsigned int u = __float_as_uint(f);
    u += 0x7fffu + ((u >> 16) & 1u);
    return (unsigned short)(u >> 16);
}
__device__ __forceinline__ float b2f(unsigned short u) {
    return __uint_as_float(((unsigned int)u) << 16);
}
__device__ __forceinline__ int finite_f(float v) {
    return ((__float_as_uint(v) >> 23) & 0xFFu) != 0xFFu;
}
// hardware v_exp_f32 computes 2^x (input in log2 domain)
__device__ __forceinline__ float exp2_hw(float x) {
    return __builtin_amdgcn_exp2f(x);
}

// ---------------- input-dtype detector ----------------
__global__ __launch_bounds__(64) void detect_k(const unsigned int* __restrict__ x,
                                               int* __restrict__ flag) {
    int tid = threadIdx.x;
    int cnt = 0;
#pragma unroll
    for (int i = 0; i < 16; ++i) {
        unsigned int w = x[tid * 16 + i];
        unsigned int lo = w & 0xFFFFu;
        unsigned int e = (lo >> 7) & 0xFFu;
        if ((e >= 0x62u && e <= 0x90u) || lo == 0u) ++cnt;
    }
#pragma unroll
    for (int o = 32; o; o >>= 1) cnt += __shfl_down(cnt, o);
    if (tid == 0) *flag = (cnt >= 640) ? 1 : 0;   // of 1024
}

// ------------- W transpose(+cast): [R][Cc] -> bf16 [Cc][R] -------------
__global__ __launch_bounds__(256) void wtrans_k(const void* __restrict__ in,
                                                unsigned short* __restrict__ out,
                                                int R, int Cc,
                                                const int* __restrict__ flag) {
    __shared__ float tile[32][33];
    const int tid = threadIdx.x;
    const int c0 = blockIdx.x * 32, r0 = blockIdx.y * 32;
    const int isb = *flag;
#pragma unroll
    for (int i = 0; i < 4; ++i) {
        int e = i * 256 + tid;
        int row = e >> 5, col = e & 31;
        size_t idx = (size_t)(r0 + row) * Cc + (c0 + col);
        tile[row][col] = isb ? b2f(((const unsigned short*)in)[idx])
                             : ((const float*)in)[idx];
    }
    __syncthreads();
#pragma unroll
    for (int i = 0; i < 4; ++i) {
        int e = i * 256 + tid;
        int crow = e >> 5, rcol = e & 31;
        out[(size_t)(c0 + crow) * R + (r0 + rcol)] = f2b(tile[rcol][crow]);
    }
}

// ------------- V transpose: bf16 [bh][2048][64] -> [bh][64][2048] -------------
__global__ __launch_bounds__(256) void vtrans_k(const unsigned short* __restrict__ V,
                                                unsigned short* __restrict__ VT) {
    __shared__ unsigned short tile[64][68];
    const int tid = threadIdx.x;
    const int t0 = blockIdx.x * 64;
    const int bh = blockIdx.y;
    const unsigned short* in = V + ((size_t)bh * TT + t0) * DD;
#pragma unroll
    for (int i = 0; i < 4; ++i) {
        int cid = i * 256 + tid;
        int row = cid >> 4;
        int ch  = cid & 15;
        u16x4 v = *(const u16x4*)(in + row * DD + ch * 4);
        *(u16x4*)&tile[row][ch * 4] = v;
    }
    __syncthreads();
    unsigned short* out = VT + (size_t)bh * DD * TT + t0;
#pragma unroll
    for (int i = 0; i < 4; ++i) {
        int cid = i * 256 + tid;
        int drow = cid >> 4;
        int tch  = cid & 15;
        u16x4 v;
        v[0] = tile[tch * 4 + 0][drow];
        v[1] = tile[tch * 4 + 1][drow];
        v[2] = tile[tch * 4 + 2][drow];
        v[3] = tile[tch * 4 + 3][drow];
        *(u16x4*)(out + (size_t)drow * TT + tch * 4) = v;
    }
}

// -------- QKV GEMM: x[M][K] (fp32|bf16) @ WqkvT[N][K] bf16 + bias --------
// scatter: Q (x 0.125*log2e) -> Qb, K -> Kb  ([B,H,T,D] bf16);  V -> d_out
__global__ __launch_bounds__(256) void gemm_qkv(const void* __restrict__ x,
                                                const unsigned short* __restrict__ Bt,
                                                const void* __restrict__ bias,
                                                unsigned short* __restrict__ outQ,
                                                unsigned short* __restrict__ outK,
                                                unsigned short* __restrict__ outV,
                                                const int* __restrict__ flag) {
    __shared__ unsigned short As[128 * 32];
    __shared__ unsigned short Bs[128 * 32];
    const int Ksz = CCH;
    const int tid = threadIdx.x;
    const int lane = tid & 63;
    const int wid = tid >> 6;
    const int bm = blockIdx.y * 128;
    const int bn = blockIdx.x * 128;
    const int wm = (wid >> 1) * 64;
    const int wn = (wid & 1) * 64;
    const int sr = tid >> 2;
    const int sc = (tid & 3) * 8;
    const int l15 = lane & 15, l4 = lane >> 4;
    const int isb = *flag;

    f32x4 acc[4][4];
#pragma unroll
    for (int i = 0; i < 4; ++i)
#pragma unroll
        for (int j = 0; j < 4; ++j)
            acc[i][j] = (f32x4){0.f, 0.f, 0.f, 0.f};

    const size_t aoff0 = (size_t)(bm + sr) * Ksz + sc;
    const size_t aoff1 = aoff0 + (size_t)64 * Ksz;
    const unsigned short* pb0 = Bt + (size_t)(bn + sr) * Ksz + sc;
    const unsigned short* pb1 = pb0 + (size_t)64 * Ksz;

    auto lda = [&](size_t off) -> u16x8 {
        if (isb) return *(const u16x8*)((const unsigned short*)x + off);
        const float4* p = (const float4*)((const float*)x + off);
        float4 v0 = p[0], v1 = p[1];
        u16x8 o;
        o[0] = f2b(v0.x); o[1] = f2b(v0.y); o[2] = f2b(v0.z); o[3] = f2b(v0.w);
        o[4] = f2b(v1.x); o[5] = f2b(v1.y); o[6] = f2b(v1.z); o[7] = f2b(v1.w);
        return o;
    };

    u16x8 a0 = lda(aoff0);
    u16x8 a1 = lda(aoff1);
    u16x8 b0 = *(const u16x8*)(pb0);
    u16x8 b1 = *(const u16x8*)(pb1);

    for (int kt = 0; kt < Ksz; kt += 32) {
        __syncthreads();
        *(u16x8*)&As[sr * 32 + sc] = a0;
        *(u16x8*)&As[(sr + 64) * 32 + sc] = a1;
        *(u16x8*)&Bs[sr * 32 + sc] = b0;
        *(u16x8*)&Bs[(sr + 64) * 32 + sc] = b1;
        if (kt + 32 < Ksz) {
            a0 = lda(aoff0 + kt + 32);
            a1 = lda(aoff1 + kt + 32);
            b0 = *(const u16x8*)(pb0 + kt + 32);
            b1 = *(const u16x8*)(pb1 + kt + 32);
        }
        __syncthreads();
        short8 af[4], bfr[4];
#pragma unroll
        for (int mi = 0; mi < 4; ++mi)
            af[mi] = *(const short8*)&As[(wm + mi * 16 + l15) * 32 + l4 * 8];
#pragma unroll
        for (int ni = 0; ni < 4; ++ni)
            bfr[ni] = *(const short8*)&Bs[(wn + ni * 16 + l15) * 32 + l4 * 8];
#pragma unroll
        for (int mi = 0; mi < 4; ++mi)
#pragma unroll
            for (int ni = 0; ni < 4; ++ni)
                acc[mi][ni] = __builtin_amdgcn_mfma_f32_16x16x32_bf16(
                    af[mi], bfr[ni], acc[mi][ni], 0, 0, 0);
    }

    // epilogue: C/D layout col=lane&15, row=(lane>>4)*4+reg  [m89/m91]
#pragma unroll
    for (int mi = 0; mi < 4; ++mi) {
#pragma unroll
        for (int ni = 0; ni < 4; ++ni) {
            const int col = bn + wn + ni * 16 + l15;
            const float bv = isb ? b2f(((const unsigned short*)bias)[col])
                                 : ((const float*)bias)[col];
#pragma unroll
            for (int r = 0; r < 4; ++r) {
                const int row = bm + wm + mi * 16 + l4 * 4 + r;
                float v = acc[mi][ni][r] + bv;
                const int which = col >> 10;
                const int h = (col >> 6) & 15;
                const int d = col & 63;
                const int b = row >> 11, t = row & 2047;
                const size_t idx = (((size_t)b * HH + h) * TT + t) * DD + d;
                // Q scale = 1/sqrt(64) * log2(e): attn softmax uses exp2
                if (which == 0)      outQ[idx] = f2b(v * 0.18033688f);
                else if (which == 1) outK[idx] = f2b(v);
                else                 outV[idx] = f2b(v);
            }
        }
    }
}

// ---------------- flash attention v2 ----------------
// 1 wave per 16 q-rows; each wave processes TWO q-tiles {qt, 127-qt} so every
// wave does a constant 2064 kpos of causal work (fixes triangular imbalance).
// KVBLK=64 per iteration; P round-trip through XOR-swizzled 128B LDS rows;
// V fragments preloaded before the softmax VALU chain.
// Q pre-scaled by 0.125*log2e -> softmax in exp2 domain (identical result).
__global__ __launch_bounds__(256) void attn_k(unsigned short* __restrict__ Q,
                                              const unsigned short* __restrict__ K,
                                              const unsigned short* __restrict__ VT) {
    __shared__ unsigned short Plds[4][16][64];   // 128-B rows, XOR-swizzled
    __shared__ unsigned short Olds[4][64][18];   // +2 pad: conflict-free epilogue
    const int tid = threadIdx.x, lane = tid & 63, wid = tid >> 6;
    const int gw = blockIdx.x * 4 + wid;        // 0..4095
    const int bh = gw >> 6;                     // 0..63
    const int pair = gw & 63;                   // balanced tile pair index
    const int l15 = lane & 15, l4 = lane >> 4;
    unsigned short* Qp = Q + (size_t)bh * TT * DD;
    const unsigned short* Kp = K + (size_t)bh * TT * DD;
    const unsigned short* Vp = VT + (size_t)bh * DD * TT;
    const int swz = (l15 & 7) << 4;             // byte-XOR within 128B row [G4]
    unsigned char* prow = (unsigned char*)&Plds[wid][l15][0];

#pragma unroll 1
    for (int hv = 0; hv < 2; ++hv) {
        const int qt = hv ? (127 - pair) : pair;
        const int qw = qt << 4;
        const int qi = qw + l15;
        const int kendR = (qw + 16 + 63) & ~63;   // round up to KVBLK

        short8 qf0 = *(const short8*)(Qp + (size_t)(qw + l15) * DD + l4 * 8);
        short8 qf1 = *(const short8*)(Qp + (size_t)(qw + l15) * DD + 32 + l4 * 8);

        f32x4 ot[4];
#pragma unroll
        for (int c = 0; c < 4; ++c) ot[c] = (f32x4){0.f, 0.f, 0.f, 0.f};
        float m = -1e30f, lsum = 0.f;

#pragma unroll 1
        for (int kb = 0; kb < kendR; kb += 64) {
            // S^T[kpos][q] = K . Q^T for 4 sixteen-row K tiles
            f32x4 st[4];
#pragma unroll
            for (int t = 0; t < 4; ++t) {
                const unsigned short* kr = Kp + (size_t)(kb + t * 16 + l15) * DD + l4 * 8;
                short8 kf0 = *(const short8*)(kr);
                short8 kf1 = *(const short8*)(kr + 32);
                f32x4 z = (f32x4){0.f, 0.f, 0.f, 0.f};
                z = __builtin_amdgcn_mfma_f32_16x16x32_bf16(kf0, qf0, z, 0, 0, 0);
                z = __builtin_amdgcn_mfma_f32_16x16x32_bf16(kf1, qf1, z, 0, 0, 0);
                st[t] = z;
            }
            // V fragments: independent of softmax -> issue now, consume later
            short8 vf[4][2];
#pragma unroll
            for (int c = 0; c < 4; ++c)
#pragma unroll
                for (int ch = 0; ch < 2; ++ch)
                    vf[c][ch] = *(const short8*)(Vp + (size_t)(c * 16 + l15) * TT
                                                 + kb + ch * 32 + l4 * 8);
            // causal mask + online softmax (exp2 domain)
            float sv[16];
            float tmax = -1e30f;
#pragma unroll
            for (int t = 0; t < 4; ++t)
#pragma unroll
                for (int r = 0; r < 4; ++r) {
                    const int kpos = kb + t * 16 + l4 * 4 + r;
                    float v = st[t][r];
                    v = (kpos > qi) ? -30000.f : v;
                    sv[t * 4 + r] = v;
                    tmax = fmaxf(tmax, v);
                }
            tmax = fmaxf(tmax, __shfl_xor(tmax, 16));
            tmax = fmaxf(tmax, __shfl_xor(tmax, 32));
            const float mnew = fmaxf(m, tmax);
            const float corr = exp2_hw(m - mnew);
            float psum = 0.f;
            u16x4 pw[4];
#pragma unroll
            for (int t = 0; t < 4; ++t)
#pragma unroll
                for (int r = 0; r < 4; ++r) {
                    float p = exp2_hw(sv[t * 4 + r] - mnew);
                    psum += p;
                    pw[t][r] = f2b(p);
                }
            lsum = lsum * corr + psum;   // per-lane partial; reduced in epilogue
            m = mnew;
#pragma unroll
            for (int c = 0; c < 4; ++c) ot[c] *= corr;
            // P -> LDS (swizzled write), read back as PV B-fragments
#pragma unroll
            for (int t = 0; t < 4; ++t)
                *(u16x4*)(prow + ((t * 32 + l4 * 8) ^ swz)) = pw[t];
            asm volatile("" ::: "memory");
            short8 pb0 = *(const short8*)(prow + ((l4 * 16) ^ swz));
            short8 pb1 = *(const short8*)(prow + ((64 + l4 * 16) ^ swz));
            asm volatile("" ::: "memory");
            // O^T[d][q] += V^T[d][kpos] . P[kpos][q]
#pragma unroll
            for (int c = 0; c < 4; ++c) {
                ot[c] = __builtin_amdgcn_mfma_f32_16x16x32_bf16(vf[c][0], pb0, ot[c], 0, 0, 0);
                ot[c] = __builtin_amdgcn_mfma_f32_16x16x32_bf16(vf[c][1], pb1, ot[c], 0, 0, 0);
            }
        }

        // row denominator = sum of 4 l4-group partials (m was row-uniform)
        float ls = lsum + __shfl_xor(lsum, 16);
        ls += __shfl_xor(ls, 32);
        const float inv = 1.f / ls;
#pragma unroll
        for (int c = 0; c < 4; ++c)
#pragma unroll
            for (int r = 0; r < 4; ++r) {
                float v = ot[c][r] * inv;
                if (!finite_f(v)) v = 200.0f;   // canary: attention-stage corruption
                Olds[wid][c * 16 + l4 * 4 + r][l15] = f2b(v);
            }
        asm volatile("" ::: "memory");
        const int q2 = lane >> 2, c8 = lane & 3;
#pragma unroll
        for (int s = 0; s < 2; ++s) {
            u16x8 o;
#pragma unroll
            for (int j = 0; j < 8; ++j) o[j] = Olds[wid][s * 32 + c8 * 8 + j][q2];
            *(u16x8*)(Qp + (size_t)(qw + q2) * DD + s * 32 + c8 * 8) = o;
        }
        asm volatile("" ::: "memory");   // order vs next half's Olds writes
    }
}

// -------- proj GEMM: Y([b][h][t][d] in Q region) @ WprojT + bias -> out fp32 --------
__global__ __launch_bounds__(256) void gemm_proj(const unsigned short* __restrict__ A,
                                                 const unsigned short* __restrict__ Bt,
                                                 const void* __restrict__ bias,
                                                 float* __restrict__ outO,
                                                 const int* __restrict__ flag) {
    __shared__ unsigned short As[128 * 32];
    __shared__ unsigned short Bs[128 * 32];
    const int Ksz = CCH;
    const int tid = threadIdx.x;
    const int lane = tid & 63;
    const int wid = tid >> 6;
    const int bm = blockIdx.y * 128;
    const int bn = blockIdx.x * 128;
    const int wm = (wid >> 1) * 64;
    const int wn = (wid & 1) * 64;
    const int sr = tid >> 2;
    const int sc = (tid & 3) * 8;
    const int l15 = lane & 15, l4 = lane >> 4;
    const int isb = *flag;

    f32x4 acc[4][4];
#pragma unroll
    for (int i = 0; i < 4; ++i)
#pragma unroll
        for (int j = 0; j < 4; ++j)
            acc[i][j] = (f32x4){0.f, 0.f, 0.f, 0.f};

    const int m0 = bm + sr;
    const unsigned short* Ar0 = A + (size_t)(m0 >> 11) * (HH * TT * DD)
                                  + (size_t)(m0 & 2047) * DD;
    const unsigned short* Ar1 = Ar0 + (size_t)64 * DD;
    const unsigned short* pb0 = Bt + (size_t)(bn + sr) * Ksz + sc;
    const unsigned short* pb1 = pb0 + (size_t)64 * Ksz;

    auto aoff = [&](int kt) -> size_t {
        return (size_t)(kt >> 6) * (TT * DD) + (kt & 32) + sc;
    };

    u16x8 a0 = *(const u16x8*)(Ar0 + aoff(0));
    u16x8 a1 = *(const u16x8*)(Ar1 + aoff(0));
    u16x8 b0 = *(const u16x8*)(pb0);
    u16x8 b1 = *(const u16x8*)(pb1);

    for (int kt = 0; kt < Ksz; kt += 32) {
        __syncthreads();
        *(u16x8*)&As[sr * 32 + sc] = a0;
        *(u16x8*)&As[(sr + 64) * 32 + sc] = a1;
        *(u16x8*)&Bs[sr * 32 + sc] = b0;
        *(u16x8*)&Bs[(sr + 64) * 32 + sc] = b1;
        if (kt + 32 < Ksz) {
            a0 = *(const u16x8*)(Ar0 + aoff(kt + 32));
            a1 = *(const u16x8*)(Ar1 + aoff(kt + 32));
            b0 = *(const u16x8*)(pb0 + kt + 32);
            b1 = *(const u16x8*)(pb1 + kt + 32);
        }
        __syncthreads();
        short8 af[4], bfr[4];
#pragma unroll
        for (int mi = 0; mi < 4; ++mi)
            af[mi] = *(const short8*)&As[(wm + mi * 16 + l15) * 32 + l4 * 8];
#pragma unroll
        for (int ni = 0; ni < 4; ++ni)
            bfr[ni] = *(const short8*)&Bs[(wn + ni * 16 + l15) * 32 + l4 * 8];
#pragma unroll
        for (int mi = 0; mi < 4; ++mi)
#pragma unroll
            for (int ni = 0; ni < 4; ++ni)
                acc[mi][ni] = __builtin_amdgcn_mfma_f32_16x16x32_bf16(
                    af[mi], bfr[ni], acc[mi][ni], 0, 0, 0);
    }

#pragma unroll
    for (int mi = 0; mi < 4; ++mi) {
#pragma unroll
        for (int ni = 0; ni < 4; ++ni) {
            const int col = bn + wn + ni * 16 + l15;
            const float bv = isb ? b2f(((const unsigned short*)bias)[col])
                                 : ((const float*)bias)[col];
#pragma unroll
            for (int r = 0; r < 4; ++r) {
                const int row = bm + wm + mi * 16 + l4 * 4 + r;
                float v = acc[mi][ni][r] + bv;
                if (!finite_f(v)) v = 300.0f;   // canary: proj-stage corruption
                outO[(size_t)row * CCH + col] = v;
            }
        }
    }
}

extern "C" void kernel_launch(void* const* d_in, const int* in_sizes, int n_in,
                              void* d_out, int out_size, void* d_ws, size_t ws_size,
                              hipStream_t stream) {
    const void* x     = d_in[0];
    const void* Wqkv  = d_in[1];
    const void* bqkv  = d_in[2];
    const void* Wproj = d_in[3];
    const void* bproj = d_in[4];
    float* out = (float*)d_out;   // fp32 output

    // workspace layout: 58.7 MB total (fits 64 MiB)
    char* w = (char*)d_ws;
    int* flag = (int*)w;                          w += 256;
    unsigned short* wqkvT  = (unsigned short*)w;  w += (size_t)3 * CCH * CCH * 2; // 6.3 MB
    unsigned short* wprojT = (unsigned short*)w;  w += (size_t)CCH * CCH * 2;     // 2.1 MB
    unsigned short* Qb     = (unsigned short*)w;  w += (size_t)MM * CCH * 2;      // 16.8 MB
    unsigned short* Kb     = (unsigned short*)w;  w += (size_t)MM * CCH * 2;      // 16.8 MB
    unsigned short* VTb    = (unsigned short*)w;  w += (size_t)MM * CCH * 2;      // 16.8 MB
    unsigned short* Vstage = (unsigned short*)d_out;  // d_out as V scratch

    detect_k<<<1, 64, 0, stream>>>((const unsigned int*)x, flag);
    wtrans_k<<<dim3(96, 32), 256, 0, stream>>>(Wqkv, wqkvT, CCH, 3 * CCH, flag);
    wtrans_k<<<dim3(32, 32), 256, 0, stream>>>(Wproj, wprojT, CCH, CCH, flag);
    gemm_qkv<<<dim3(24, 64), 256, 0, stream>>>(x, wqkvT, bqkv, Qb, Kb, Vstage, flag);
    vtrans_k<<<dim3(32, 64), 256, 0, stream>>>(Vstage, VTb);
    attn_k<<<1024, 256, 0, stream>>>(Qb, Kb, VTb);          // writes Y over Q rows
    gemm_proj<<<dim3(8, 64), 256, 0, stream>>>(Qb, wprojT, bproj, out, flag);
}

// Round 8
// 389.401 us; speedup vs baseline: 1.5227x; 1.1292x over previous
//
#include <hip/hip_runtime.h>
#include <hip/hip_bf16.h>

#define TT 2048
#define CCH 1024
#define HH 16
#define DD 64
#define BB 4
#define MM (BB*TT)

typedef __attribute__((ext_vector_type(4))) float f32x4;
typedef __attribute__((ext_vector_type(8))) short short8;
typedef __attribute__((ext_vector_type(8))) unsigned short u16x8;
typedef __attribute__((ext_vector_type(4))) unsigned short u16x4;

__device__ __forceinline__ unsigned short f2b(float f) {
    // fp32 -> bf16 round-to-nearest-even (finite inputs)
    unsigned int u = __float_as_uint(f);
    u += 0x7fffu + ((u >> 16) & 1u);
    return (unsigned short)(u >> 16);
}
__device__ __forceinline__ float b2f(unsigned short u) {
    return __uint_as_float(((unsigned int)u) << 16);
}
__device__ __forceinline__ int finite_f(float v) {
    return ((__float_as_uint(v) >> 23) & 0xFFu) != 0xFFu;
}
// hardware v_exp_f32 computes 2^x (input in log2 domain)
__device__ __forceinline__ float exp2_hw(float x) {
    return __builtin_amdgcn_exp2f(x);
}

// ---------------- input-dtype detector ----------------
__global__ __launch_bounds__(64) void detect_k(const unsigned int* __restrict__ x,
                                               int* __restrict__ flag) {
    int tid = threadIdx.x;
    int cnt = 0;
#pragma unroll
    for (int i = 0; i < 16; ++i) {
        unsigned int w = x[tid * 16 + i];
        unsigned int lo = w & 0xFFFFu;
        unsigned int e = (lo >> 7) & 0xFFu;
        if ((e >= 0x62u && e <= 0x90u) || lo == 0u) ++cnt;
    }
#pragma unroll
    for (int o = 32; o; o >>= 1) cnt += __shfl_down(cnt, o);
    if (tid == 0) *flag = (cnt >= 640) ? 1 : 0;   // of 1024
}

// ------------- W transpose(+cast): [R][Cc] -> bf16 [Cc][R] -------------
__global__ __launch_bounds__(256) void wtrans_k(const void* __restrict__ in,
                                                unsigned short* __restrict__ out,
                                                int R, int Cc,
                                                const int* __restrict__ flag) {
    __shared__ float tile[32][33];
    const int tid = threadIdx.x;
    const int c0 = blockIdx.x * 32, r0 = blockIdx.y * 32;
    const int isb = *flag;
#pragma unroll
    for (int i = 0; i < 4; ++i) {
        int e = i * 256 + tid;
        int row = e >> 5, col = e & 31;
        size_t idx = (size_t)(r0 + row) * Cc + (c0 + col);
        tile[row][col] = isb ? b2f(((const unsigned short*)in)[idx])
                             : ((const float*)in)[idx];
    }
    __syncthreads();
#pragma unroll
    for (int i = 0; i < 4; ++i) {
        int e = i * 256 + tid;
        int crow = e >> 5, rcol = e & 31;
        out[(size_t)(c0 + crow) * R + (r0 + rcol)] = f2b(tile[rcol][crow]);
    }
}

// ------------- V transpose: bf16 [bh][2048][64] -> [bh][64][2048] -------------
__global__ __launch_bounds__(256) void vtrans_k(const unsigned short* __restrict__ V,
                                                unsigned short* __restrict__ VT) {
    __shared__ unsigned short tile[64][68];
    const int tid = threadIdx.x;
    const int t0 = blockIdx.x * 64;
    const int bh = blockIdx.y;
    const unsigned short* in = V + ((size_t)bh * TT + t0) * DD;
#pragma unroll
    for (int i = 0; i < 4; ++i) {
        int cid = i * 256 + tid;
        int row = cid >> 4;
        int ch  = cid & 15;
        u16x4 v = *(const u16x4*)(in + row * DD + ch * 4);
        *(u16x4*)&tile[row][ch * 4] = v;
    }
    __syncthreads();
    unsigned short* out = VT + (size_t)bh * DD * TT + t0;
#pragma unroll
    for (int i = 0; i < 4; ++i) {
        int cid = i * 256 + tid;
        int drow = cid >> 4;
        int tch  = cid & 15;
        u16x4 v;
        v[0] = tile[tch * 4 + 0][drow];
        v[1] = tile[tch * 4 + 1][drow];
        v[2] = tile[tch * 4 + 2][drow];
        v[3] = tile[tch * 4 + 3][drow];
        *(u16x4*)(out + (size_t)drow * TT + tch * 4) = v;
    }
}

// -------- QKV GEMM: x[M][K] (fp32|bf16) @ WqkvT[N][K] bf16 + bias --------
// scatter: Q (x 0.125*log2e) -> Qb, K -> Kb  ([B,H,T,D] bf16);  V -> d_out
__global__ __launch_bounds__(256) void gemm_qkv(const void* __restrict__ x,
                                                const unsigned short* __restrict__ Bt,
                                                const void* __restrict__ bias,
                                                unsigned short* __restrict__ outQ,
                                                unsigned short* __restrict__ outK,
                                                unsigned short* __restrict__ outV,
                                                const int* __restrict__ flag) {
    __shared__ unsigned short As[128 * 32];
    __shared__ unsigned short Bs[128 * 32];
    const int Ksz = CCH;
    const int tid = threadIdx.x;
    const int lane = tid & 63;
    const int wid = tid >> 6;
    const int bm = blockIdx.y * 128;
    const int bn = blockIdx.x * 128;
    const int wm = (wid >> 1) * 64;
    const int wn = (wid & 1) * 64;
    const int sr = tid >> 2;
    const int sc = (tid & 3) * 8;
    const int l15 = lane & 15, l4 = lane >> 4;
    const int isb = *flag;

    f32x4 acc[4][4];
#pragma unroll
    for (int i = 0; i < 4; ++i)
#pragma unroll
        for (int j = 0; j < 4; ++j)
            acc[i][j] = (f32x4){0.f, 0.f, 0.f, 0.f};

    const size_t aoff0 = (size_t)(bm + sr) * Ksz + sc;
    const size_t aoff1 = aoff0 + (size_t)64 * Ksz;
    const unsigned short* pb0 = Bt + (size_t)(bn + sr) * Ksz + sc;
    const unsigned short* pb1 = pb0 + (size_t)64 * Ksz;

    auto lda = [&](size_t off) -> u16x8 {
        if (isb) return *(const u16x8*)((const unsigned short*)x + off);
        const float4* p = (const float4*)((const float*)x + off);
        float4 v0 = p[0], v1 = p[1];
        u16x8 o;
        o[0] = f2b(v0.x); o[1] = f2b(v0.y); o[2] = f2b(v0.z); o[3] = f2b(v0.w);
        o[4] = f2b(v1.x); o[5] = f2b(v1.y); o[6] = f2b(v1.z); o[7] = f2b(v1.w);
        return o;
    };

    u16x8 a0 = lda(aoff0);
    u16x8 a1 = lda(aoff1);
    u16x8 b0 = *(const u16x8*)(pb0);
    u16x8 b1 = *(const u16x8*)(pb1);

    for (int kt = 0; kt < Ksz; kt += 32) {
        __syncthreads();
        *(u16x8*)&As[sr * 32 + sc] = a0;
        *(u16x8*)&As[(sr + 64) * 32 + sc] = a1;
        *(u16x8*)&Bs[sr * 32 + sc] = b0;
        *(u16x8*)&Bs[(sr + 64) * 32 + sc] = b1;
        if (kt + 32 < Ksz) {
            a0 = lda(aoff0 + kt + 32);
            a1 = lda(aoff1 + kt + 32);
            b0 = *(const u16x8*)(pb0 + kt + 32);
            b1 = *(const u16x8*)(pb1 + kt + 32);
        }
        __syncthreads();
        short8 af[4], bfr[4];
#pragma unroll
        for (int mi = 0; mi < 4; ++mi)
            af[mi] = *(const short8*)&As[(wm + mi * 16 + l15) * 32 + l4 * 8];
#pragma unroll
        for (int ni = 0; ni < 4; ++ni)
            bfr[ni] = *(const short8*)&Bs[(wn + ni * 16 + l15) * 32 + l4 * 8];
#pragma unroll
        for (int mi = 0; mi < 4; ++mi)
#pragma unroll
            for (int ni = 0; ni < 4; ++ni)
                acc[mi][ni] = __builtin_amdgcn_mfma_f32_16x16x32_bf16(
                    af[mi], bfr[ni], acc[mi][ni], 0, 0, 0);
    }

    // epilogue: C/D layout col=lane&15, row=(lane>>4)*4+reg  [m89/m91]
#pragma unroll
    for (int mi = 0; mi < 4; ++mi) {
#pragma unroll
        for (int ni = 0; ni < 4; ++ni) {
            const int col = bn + wn + ni * 16 + l15;
            const float bv = isb ? b2f(((const unsigned short*)bias)[col])
                                 : ((const float*)bias)[col];
#pragma unroll
            for (int r = 0; r < 4; ++r) {
                const int row = bm + wm + mi * 16 + l4 * 4 + r;
                float v = acc[mi][ni][r] + bv;
                const int which = col >> 10;
                const int h = (col >> 6) & 15;
                const int d = col & 63;
                const int b = row >> 11, t = row & 2047;
                const size_t idx = (((size_t)b * HH + h) * TT + t) * DD + d;
                // Q scale = 1/sqrt(64) * log2(e): attn softmax uses exp2
                if (which == 0)      outQ[idx] = f2b(v * 0.18033688f);
                else if (which == 1) outK[idx] = f2b(v);
                else                 outV[idx] = f2b(v);
            }
        }
    }
}

// ---------------- flash attention v3: split-KV + prefetch ----------------
// Block = 4 waves = 2 q-tile-pairs; each pair {qt,127-qt} handled by TWO waves
// (h=0,1) splitting the KV range into even/odd 64-blocks (stride 128).
// Partials (m, l, O) merged via LDS; h=0 wave writes the output over Q rows.
// K fragments software-pipelined one iteration ahead.
__global__ __launch_bounds__(256) void attn_k(unsigned short* __restrict__ Q,
                                              const unsigned short* __restrict__ K,
                                              const unsigned short* __restrict__ VT) {
    __shared__ unsigned short Plds[4][16][64];   // swizzled P round-trip
    __shared__ unsigned short Olds[4][64][18];   // epilogue transpose
    __shared__ float Mrg[2][2][64][18];          // [pair][h][lane][{m,l,ot[16]}]
    const int tid = threadIdx.x, lane = tid & 63, wid = tid >> 6;
    const int bid = blockIdx.x;
    const int swb = (bid & 7) * 256 + (bid >> 3);   // XCD swizzle (bijective: 2048%8==0)
    const int bh = swb >> 5;                    // 0..63
    const int bp = swb & 31;                    // 0..31
    const int pi = wid >> 1, h = wid & 1;       // pair-in-block, KV half
    const int pair = bp * 2 + pi;               // 0..63
    const int l15 = lane & 15, l4 = lane >> 4;
    unsigned short* Qp = Q + (size_t)bh * TT * DD;
    const unsigned short* Kp = K + (size_t)bh * TT * DD;
    const unsigned short* Vp = VT + (size_t)bh * DD * TT;
    const int swz = (l15 & 7) << 4;             // byte-XOR within 128B row [G4]
    unsigned char* prow = (unsigned char*)&Plds[wid][l15][0];

#pragma unroll 1
    for (int hv = 0; hv < 2; ++hv) {
        const int qt = hv ? (127 - pair) : pair;
        const int qw = qt << 4;
        const int qi = qw + l15;
        const int kend = qw + 16;

        short8 qf0 = *(const short8*)(Qp + (size_t)(qw + l15) * DD + l4 * 8);
        short8 qf1 = *(const short8*)(Qp + (size_t)(qw + l15) * DD + 32 + l4 * 8);

        f32x4 ot[4];
#pragma unroll
        for (int c = 0; c < 4; ++c) ot[c] = (f32x4){0.f, 0.f, 0.f, 0.f};
        float m = -1e30f, lsum = 0.f;

        int kb = h * 64;
        short8 ka[4][2];                         // current K fragments
        if (kb < kend) {
#pragma unroll
            for (int t = 0; t < 4; ++t) {
                const unsigned short* kr = Kp + (size_t)(kb + t * 16 + l15) * DD + l4 * 8;
                ka[t][0] = *(const short8*)(kr);
                ka[t][1] = *(const short8*)(kr + 32);
            }
        }
#pragma unroll 1
        for (; kb < kend; kb += 128) {
            // QK^T on current K fragments
            f32x4 st[4];
#pragma unroll
            for (int t = 0; t < 4; ++t) {
                f32x4 z = (f32x4){0.f, 0.f, 0.f, 0.f};
                z = __builtin_amdgcn_mfma_f32_16x16x32_bf16(ka[t][0], qf0, z, 0, 0, 0);
                z = __builtin_amdgcn_mfma_f32_16x16x32_bf16(ka[t][1], qf1, z, 0, 0, 0);
                st[t] = z;
            }
            // prefetch next iteration's K (latency hides under softmax+PV)
            const bool more = (kb + 128) < kend;
            short8 kn[4][2];
            if (more) {
#pragma unroll
                for (int t = 0; t < 4; ++t) {
                    const unsigned short* kr = Kp + (size_t)(kb + 128 + t * 16 + l15) * DD + l4 * 8;
                    kn[t][0] = *(const short8*)(kr);
                    kn[t][1] = *(const short8*)(kr + 32);
                }
            }
            // V fragments (consumed after softmax -> latency hidden)
            short8 vf[4][2];
#pragma unroll
            for (int c = 0; c < 4; ++c)
#pragma unroll
                for (int ch = 0; ch < 2; ++ch)
                    vf[c][ch] = *(const short8*)(Vp + (size_t)(c * 16 + l15) * TT
                                                 + kb + ch * 32 + l4 * 8);
            // causal mask (in place) + row max
            float tmax = -1e30f;
#pragma unroll
            for (int t = 0; t < 4; ++t)
#pragma unroll
                for (int r = 0; r < 4; ++r) {
                    const int kpos = kb + t * 16 + l4 * 4 + r;
                    float v = st[t][r];
                    v = (kpos > qi) ? -30000.f : v;
                    st[t][r] = v;
                    tmax = fmaxf(tmax, v);
                }
            tmax = fmaxf(tmax, __shfl_xor(tmax, 16));
            tmax = fmaxf(tmax, __shfl_xor(tmax, 32));
            const float mnew = fmaxf(m, tmax);
            const float corr = exp2_hw(m - mnew);
            float psum = 0.f;
            u16x4 pw[4];
#pragma unroll
            for (int t = 0; t < 4; ++t)
#pragma unroll
                for (int r = 0; r < 4; ++r) {
                    float p = exp2_hw(st[t][r] - mnew);
                    psum += p;
                    pw[t][r] = f2b(p);
                }
            lsum = lsum * corr + psum;   // per-lane partial; reduced later
            m = mnew;
#pragma unroll
            for (int c = 0; c < 4; ++c) ot[c] *= corr;
            // P -> LDS (swizzled), read back as PV B-fragments
#pragma unroll
            for (int t = 0; t < 4; ++t)
                *(u16x4*)(prow + ((t * 32 + l4 * 8) ^ swz)) = pw[t];
            asm volatile("" ::: "memory");
            short8 pb0 = *(const short8*)(prow + ((l4 * 16) ^ swz));
            short8 pb1 = *(const short8*)(prow + ((64 + l4 * 16) ^ swz));
            asm volatile("" ::: "memory");
            // O^T[d][q] += V^T[d][kpos] . P[kpos][q]
#pragma unroll
            for (int c = 0; c < 4; ++c) {
                ot[c] = __builtin_amdgcn_mfma_f32_16x16x32_bf16(vf[c][0], pb0, ot[c], 0, 0, 0);
                ot[c] = __builtin_amdgcn_mfma_f32_16x16x32_bf16(vf[c][1], pb1, ot[c], 0, 0, 0);
            }
            // rotate prefetched K into place
            if (more) {
#pragma unroll
                for (int t = 0; t < 4; ++t) {
                    ka[t][0] = kn[t][0];
                    ka[t][1] = kn[t][1];
                }
            }
        }

        // per-row denominator partial: sum the 4 l4-group partials
        float ls = lsum + __shfl_xor(lsum, 16);
        ls += __shfl_xor(ls, 32);

        // exchange partials with the partner wave (other KV half)
        float* mb = &Mrg[pi][h][lane][0];
        mb[0] = m;
        mb[1] = ls;
#pragma unroll
        for (int c = 0; c < 4; ++c)
#pragma unroll
            for (int r = 0; r < 4; ++r) mb[2 + c * 4 + r] = ot[c][r];
        __syncthreads();
        if (h == 0) {
            const float* pbuf = &Mrg[pi][1][lane][0];
            const float m2 = pbuf[0], l2 = pbuf[1];
            const float mstar = fmaxf(m, m2);
            const float c1 = exp2_hw(m - mstar);
            const float c2 = exp2_hw(m2 - mstar);
            const float inv = 1.f / (ls * c1 + l2 * c2);
#pragma unroll
            for (int c = 0; c < 4; ++c)
#pragma unroll
                for (int r = 0; r < 4; ++r) {
                    float v = (ot[c][r] * c1 + pbuf[2 + c * 4 + r] * c2) * inv;
                    if (!finite_f(v)) v = 200.0f;   // canary
                    Olds[wid][c * 16 + l4 * 4 + r][l15] = f2b(v);
                }
            asm volatile("" ::: "memory");
            const int q2 = lane >> 2, c8 = lane & 3;
#pragma unroll
            for (int s = 0; s < 2; ++s) {
                u16x8 o;
#pragma unroll
                for (int j = 0; j < 8; ++j) o[j] = Olds[wid][s * 32 + c8 * 8 + j][q2];
                *(u16x8*)(Qp + (size_t)(qw + q2) * DD + s * 32 + c8 * 8) = o;
            }
        }
        __syncthreads();   // protect Mrg/Olds before next hv reuses them
    }
}

// -------- proj GEMM: Y([b][h][t][d] in Q region) @ WprojT + bias -> out fp32 --------
__global__ __launch_bounds__(256) void gemm_proj(const unsigned short* __restrict__ A,
                                                 const unsigned short* __restrict__ Bt,
                                                 const void* __restrict__ bias,
                                                 float* __restrict__ outO,
                                                 const int* __restrict__ flag) {
    __shared__ unsigned short As[128 * 32];
    __shared__ unsigned short Bs[128 * 32];
    const int Ksz = CCH;
    const int tid = threadIdx.x;
    const int lane = tid & 63;
    const int wid = tid >> 6;
    const int bm = blockIdx.y * 128;
    const int bn = blockIdx.x * 128;
    const int wm = (wid >> 1) * 64;
    const int wn = (wid & 1) * 64;
    const int sr = tid >> 2;
    const int sc = (tid & 3) * 8;
    const int l15 = lane & 15, l4 = lane >> 4;
    const int isb = *flag;

    f32x4 acc[4][4];
#pragma unroll
    for (int i = 0; i < 4; ++i)
#pragma unroll
        for (int j = 0; j < 4; ++j)
            acc[i][j] = (f32x4){0.f, 0.f, 0.f, 0.f};

    const int m0 = bm + sr;
    const unsigned short* Ar0 = A + (size_t)(m0 >> 11) * (HH * TT * DD)
                                  + (size_t)(m0 & 2047) * DD;
    const unsigned short* Ar1 = Ar0 + (size_t)64 * DD;
    const unsigned short* pb0 = Bt + (size_t)(bn + sr) * Ksz + sc;
    const unsigned short* pb1 = pb0 + (size_t)64 * Ksz;

    auto aoff = [&](int kt) -> size_t {
        return (size_t)(kt >> 6) * (TT * DD) + (kt & 32) + sc;
    };

    u16x8 a0 = *(const u16x8*)(Ar0 + aoff(0));
    u16x8 a1 = *(const u16x8*)(Ar1 + aoff(0));
    u16x8 b0 = *(const u16x8*)(pb0);
    u16x8 b1 = *(const u16x8*)(pb1);

    for (int kt = 0; kt < Ksz; kt += 32) {
        __syncthreads();
        *(u16x8*)&As[sr * 32 + sc] = a0;
        *(u16x8*)&As[(sr + 64) * 32 + sc] = a1;
        *(u16x8*)&Bs[sr * 32 + sc] = b0;
        *(u16x8*)&Bs[(sr + 64) * 32 + sc] = b1;
        if (kt + 32 < Ksz) {
            a0 = *(const u16x8*)(Ar0 + aoff(kt + 32));
            a1 = *(const u16x8*)(Ar1 + aoff(kt + 32));
            b0 = *(const u16x8*)(pb0 + kt + 32);
            b1 = *(const u16x8*)(pb1 + kt + 32);
        }
        __syncthreads();
        short8 af[4], bfr[4];
#pragma unroll
        for (int mi = 0; mi < 4; ++mi)
            af[mi] = *(const short8*)&As[(wm + mi * 16 + l15) * 32 + l4 * 8];
#pragma unroll
        for (int ni = 0; ni < 4; ++ni)
            bfr[ni] = *(const short8*)&Bs[(wn + ni * 16 + l15) * 32 + l4 * 8];
#pragma unroll
        for (int mi = 0; mi < 4; ++mi)
#pragma unroll
            for (int ni = 0; ni < 4; ++ni)
                acc[mi][ni] = __builtin_amdgcn_mfma_f32_16x16x32_bf16(
                    af[mi], bfr[ni], acc[mi][ni], 0, 0, 0);
    }

#pragma unroll
    for (int mi = 0; mi < 4; ++mi) {
#pragma unroll
        for (int ni = 0; ni < 4; ++ni) {
            const int col = bn + wn + ni * 16 + l15;
            const float bv = isb ? b2f(((const unsigned short*)bias)[col])
                                 : ((const float*)bias)[col];
#pragma unroll
            for (int r = 0; r < 4; ++r) {
                const int row = bm + wm + mi * 16 + l4 * 4 + r;
                float v = acc[mi][ni][r] + bv;
                if (!finite_f(v)) v = 300.0f;   // canary: proj-stage corruption
                outO[(size_t)row * CCH + col] = v;
            }
        }
    }
}

extern "C" void kernel_launch(void* const* d_in, const int* in_sizes, int n_in,
                              void* d_out, int out_size, void* d_ws, size_t ws_size,
                              hipStream_t stream) {
    const void* x     = d_in[0];
    const void* Wqkv  = d_in[1];
    const void* bqkv  = d_in[2];
    const void* Wproj = d_in[3];
    const void* bproj = d_in[4];
    float* out = (float*)d_out;   // fp32 output

    // workspace layout: 58.7 MB total (fits 64 MiB)
    char* w = (char*)d_ws;
    int* flag = (int*)w;                          w += 256;
    unsigned short* wqkvT  = (unsigned short*)w;  w += (size_t)3 * CCH * CCH * 2; // 6.3 MB
    unsigned short* wprojT = (unsigned short*)w;  w += (size_t)CCH * CCH * 2;     // 2.1 MB
    unsigned short* Qb     = (unsigned short*)w;  w += (size_t)MM * CCH * 2;      // 16.8 MB
    unsigned short* Kb     = (unsigned short*)w;  w += (size_t)MM * CCH * 2;      // 16.8 MB
    unsigned short* VTb    = (unsigned short*)w;  w += (size_t)MM * CCH * 2;      // 16.8 MB
    unsigned short* Vstage = (unsigned short*)d_out;  // d_out as V scratch

    detect_k<<<1, 64, 0, stream>>>((const unsigned int*)x, flag);
    wtrans_k<<<dim3(96, 32), 256, 0, stream>>>(Wqkv, wqkvT, CCH, 3 * CCH, flag);
    wtrans_k<<<dim3(32, 32), 256, 0, stream>>>(Wproj, wprojT, CCH, CCH, flag);
    gemm_qkv<<<dim3(24, 64), 256, 0, stream>>>(x, wqkvT, bqkv, Qb, Kb, Vstage, flag);
    vtrans_k<<<dim3(32, 64), 256, 0, stream>>>(Vstage, VTb);
    attn_k<<<2048, 256, 0, stream>>>(Qb, Kb, VTb);          // writes Y over Q rows
    gemm_proj<<<dim3(8, 64), 256, 0, stream>>>(Qb, wprojT, bproj, out, flag);
}